// Round 5
// baseline (5313.382 us; speedup 1.0000x reference)
//
#include <hip/hip_runtime.h>

// GRU: B=64, T=2048, D=256, U=256.
//  k0: transpose weights -> bf16 [col][k]
//  k1: proj GEMM -> recurrence-native x layout (unchanged):
//      XA[t][g][w][lane] = 2 uint4: slot0 = xz[8], slot1 = xr[8]   (w = 0..7, 32 cols)
//      XB[t][g][w][lane] = 1 uint4: xh[8]
//  k2: recurrence. R9: 4 waves x 256 thr (1 wave/SIMD), wave w2 owns 64 gate
//      cols [w2*64, w2*64+64). Rationale: R3's LDS pipe was co-bottleneck
//      (128 ds_read_b128/step, every wave re-reading the same h and v). With
//      4 waves each A-fragment read feeds 2x the MFMAs -> 64 reads/step
//      (~770cy << MFMA 1536cy). 1 wave/SIMD owns the full 512-reg budget:
//      U = 96 bf16x8 frags = 384 regs + ~110 working set. In-place x prefetch
//      (no shadow regs). proj_k layout unchanged -- a 64-col wave reads the
//      two adjacent 32-col records. Math identical to R3 (absmax bit-equal).

#define TB 2048
#define NU 256
#define G3 768

typedef __attribute__((ext_vector_type(8))) short bf16x8;
typedef __attribute__((ext_vector_type(4))) float f32x4;

__device__ inline unsigned short f2bf(float f){
  union{float f; unsigned u;} v; v.f = f;
  unsigned r = v.u + 0x7fffu + ((v.u >> 16) & 1u);   // RNE
  return (unsigned short)(r >> 16);
}
__device__ inline unsigned pk2(float a, float b){
  return (unsigned)f2bf(a) | ((unsigned)f2bf(b) << 16);
}
__device__ inline float bflo(unsigned u){
  union{unsigned u; float f;} v; v.u = u << 16; return v.f;
}
__device__ inline float bfhi(unsigned u){
  union{unsigned u; float f;} v; v.u = u & 0xffff0000u; return v.f;
}
// single-instruction RNE f32->bf16 pack
__device__ inline unsigned cvtpk(float a, float b){
  unsigned r;
  asm("v_cvt_pk_bf16_f32 %0, %1, %2" : "=v"(r) : "v"(a), "v"(b));
  return r;
}
__device__ inline float exp2_fast(float x){
#if __has_builtin(__builtin_amdgcn_exp2f)
  return __builtin_amdgcn_exp2f(x);
#else
  float r; asm("v_exp_f32 %0, %1" : "=v"(r) : "v"(x)); return r;
#endif
}

// ---------------- k0: weight transpose to bf16 [col][k] ----------------
__global__ __launch_bounds__(256) void transpose_k(const float* __restrict__ W,
                                                   const float* __restrict__ R,
                                                   unsigned short* __restrict__ Wt,
                                                   unsigned short* __restrict__ Ut){
  int n = blockIdx.x;        // 0..1535
  int k = threadIdx.x;       // 0..255
  if (n < G3) Wt[n*NU + k] = f2bf(W[k*G3 + n]);
  else        Ut[(n-G3)*NU + k] = f2bf(R[k*G3 + (n-G3)]);
}

// ---------------- k1: projection GEMM ----------------
__global__ __launch_bounds__(256) void proj_k(const float* __restrict__ x,
                                              const unsigned short* __restrict__ Wt,
                                              const float* __restrict__ bias,
                                              unsigned short* __restrict__ XA,
                                              unsigned short* __restrict__ XB){
  __shared__ short As[4096];
  __shared__ short Bs[4096];
  __shared__ short St[4096];        // compact [chunk 0..7][lane 0..63][8]
  const int tid  = threadIdx.x;
  const int lane = tid & 63;
  const int wv   = tid >> 6;
  const int wr   = wv >> 1, wc = wv & 1;
  const int q    = lane >> 4, r16 = lane & 15;
  const int tm   = blockIdx.x;      // time step
  const int bn   = blockIdx.y;      // 0..11 gate-col chunk

  f32x4 acc[2][2];
  #pragma unroll
  for (int a=0;a<2;a++)
    #pragma unroll
    for (int b=0;b<2;b++) acc[a][b] = {0.f,0.f,0.f,0.f};

  const int mA = tid >> 2, kq = tid & 3;
  const int kc32 = kq >> 1, q0 = (kq & 1) * 2;

  for (int kc0 = 0; kc0 < 256; kc0 += 64){
    {
      const float* src = x + (size_t)mA*(2048*256) + (size_t)tm*256 + kc0 + kq*16;
      float4 f0 = *(const float4*)(src);
      float4 f1 = *(const float4*)(src+4);
      float4 f2 = *(const float4*)(src+8);
      float4 f3 = *(const float4*)(src+12);
      *(uint2*)&As[kc32*2048 + q0*512     + mA*8 + 0] = make_uint2(pk2(f0.x,f0.y), pk2(f0.z,f0.w));
      *(uint2*)&As[kc32*2048 + q0*512     + mA*8 + 4] = make_uint2(pk2(f1.x,f1.y), pk2(f1.z,f1.w));
      *(uint2*)&As[kc32*2048 + (q0+1)*512 + mA*8 + 0] = make_uint2(pk2(f2.x,f2.y), pk2(f2.z,f2.w));
      *(uint2*)&As[kc32*2048 + (q0+1)*512 + mA*8 + 4] = make_uint2(pk2(f3.x,f3.y), pk2(f3.z,f3.w));
    }
    {
      const unsigned short* srcB = Wt + (size_t)(bn*64 + mA)*256 + kc0 + kq*16;
      uint4 b0v = *(const uint4*)(srcB);
      uint4 b1v = *(const uint4*)(srcB+8);
      *(uint4*)&Bs[kc32*2048 + q0*512     + mA*8] = b0v;
      *(uint4*)&Bs[kc32*2048 + (q0+1)*512 + mA*8] = b1v;
    }
    __syncthreads();
    #pragma unroll
    for (int kk = 0; kk < 2; kk++){
      bf16x8 av[2], bv[2];
      #pragma unroll
      for (int rt=0; rt<2; rt++)
        av[rt] = *(const bf16x8*)&As[kk*2048 + q*512 + (wr*32+rt*16+r16)*8];
      #pragma unroll
      for (int ct=0; ct<2; ct++)
        bv[ct] = *(const bf16x8*)&Bs[kk*2048 + q*512 + (wc*32+ct*16+r16)*8];
      #pragma unroll
      for (int rt=0; rt<2; rt++)
        #pragma unroll
        for (int ct=0; ct<2; ct++)
          acc[rt][ct] = __builtin_amdgcn_mfma_f32_16x16x32_bf16(av[rt], bv[ct], acc[rt][ct], 0,0,0);
    }
    __syncthreads();
  }

  // epilogue: +bias, stage compact recurrence-native order in St
  const int csub = (bn < 4) ? 0 : (bn < 8 ? 256 : 512);
  #pragma unroll
  for (int rt=0; rt<2; rt++){
    #pragma unroll
    for (int ct=0; ct<2; ct++){
      int colg = bn*64 + wc*32 + ct*16 + r16;
      float bb = bias[colg];
      int c = colg - csub;                 // 0..255 within z / r / h
      int wi = (c >> 5) & 1, tt2 = (c >> 4) & 1, r16g = c & 15;
      #pragma unroll
      for (int i=0;i<4;i++){
        int b = wr*32 + rt*16 + q*4 + i;   // batch
        int gg = b >> 4, lb = b & 15;
        int lane_ = (lb >> 2)*16 + r16g, ii = lb & 3;
        St[(gg*2+wi)*512 + lane_*8 + tt2*4 + ii] = (short)f2bf(acc[rt][ct][i] + bb);
      }
    }
  }
  __syncthreads();

  // disjoint coalesced stores: z -> XA slot 0, r -> XA slot 1, h -> XB
  #pragma unroll
  for (int it=0; it<2; it++){
    int idx = tid + it*256;            // 0..511
    int chunk = idx >> 6, within = idx & 63;
    int gg = chunk >> 1, wi = chunk & 1;
    int w_ = (bn & 3)*2 + wi;
    uint4 val = *(const uint4*)&St[chunk*512 + within*8];
    if (bn < 8){
      int sel = (bn < 4) ? 0 : 1;
      *((uint4*)XA + ((((size_t)tm*4+gg)*8 + w_)*64 + within)*2 + sel) = val;
    } else {
      *((uint4*)XB + (((size_t)tm*4+gg)*8 + w_)*64 + within) = val;
    }
  }
}

// ---------------- k2: recurrence (4 waves, 64 cols/wave) ----------------
__global__ __launch_bounds__(256, 1) void gru_k(const unsigned short* __restrict__ XA,
                                                const unsigned short* __restrict__ XB,
                                                const unsigned short* __restrict__ Ut,
                                                float* __restrict__ out){
  // [0..4095]=h frag-order (swizzled), [4096..8191]=r*h (swizzled)
  __shared__ short fb[8192];

  const int tid  = threadIdx.x;
  const int w2   = tid >> 6;        // wave 0..3 owns unit cols [w2*64, w2*64+64)
  const int lane = tid & 63;
  const int q    = lane >> 4, r16 = lane & 15;
  const int g    = blockIdx.x;
  const int b0   = g * 16;

  // XOR bank swizzle (lane-constant on both sides, zero runtime cost)
  const int lswz = (lane & ~3) | ((lane & 3) ^ ((((lane >> 4) & 1) << 1) | ((lane >> 3) & 1)));
  const int ix   = ((r16 >> 3) << 1) | ((lane >> 5) & 1);
  // write base: addr(tt,i) = wrb + tt*256 + (i^ix)*8  (tt = 0..3 spans the two
  // old 32-col records: (2*w2+(tt>>1))*512 + (tt&1)*256 == w2*1024 + tt*256)
  const int wrb  = w2*1024 + (r16 >> 3)*128 + q*32 + (r16 & 7);

  for (int i = tid; i < 8192; i += 256) fb[i] = 0;

  // one-time U fragment load: 96 frags = 384 regs (1 wave/SIMD -> 512 budget)
  bf16x8 Uz[4][8], Ur[4][8], Uh[4][8];
  #pragma unroll
  for (int tt=0; tt<4; tt++){
    int cz = w2*64 + tt*16 + r16;
    #pragma unroll
    for (int kc=0; kc<8; kc++){
      Uz[tt][kc] = *(const bf16x8*)&Ut[(cz      )*256 + kc*32 + q*8];
      Ur[tt][kc] = *(const bf16x8*)&Ut[(cz + 256)*256 + kc*32 + q*8];
      Uh[tt][kc] = *(const bf16x8*)&Ut[(cz + 512)*256 + kc*32 + q*8];
    }
  }

  float hprev[4][4] = {{0,0,0,0},{0,0,0,0},{0,0,0,0},{0,0,0,0}};

  // old-record pointers: records for w = 2*w2 and 2*w2+1
  const uint4* pA = (const uint4*)XA + ((size_t)(g*8 + 2*w2)*64 + lane)*2;
  const uint4* pB = (const uint4*)XB + ((size_t)(g*8 + 2*w2)*64 + lane);

  // prologue load for t=0; in-loop reload in place right after consumption
  // (t=2047 over-read lands in XB / Wt workspace regions -- harmless)
  uint4 xa0 = pA[0], xa1 = pA[1], xa2 = pA[128], xa3 = pA[129];
  uint4 xb0 = pB[0], xb1 = pB[64];
  pA += 4096; pB += 2048;

  __syncthreads();

  #pragma unroll 1
  for (int t = 0; t < TB; t++){
    // ---- phase A: z,r MFMAs for own 64 gate cols; acc init = x ----
    f32x4 az[4], ar[4];
    {
      unsigned zw[8] = {xa0.x,xa0.y,xa0.z,xa0.w, xa2.x,xa2.y,xa2.z,xa2.w};
      unsigned rw[8] = {xa1.x,xa1.y,xa1.z,xa1.w, xa3.x,xa3.y,xa3.z,xa3.w};
      #pragma unroll
      for (int tt=0; tt<4; tt++){
        #pragma unroll
        for (int i=0;i<4;i++){
          unsigned uz = zw[tt*2 + (i>>1)];
          unsigned ur = rw[tt*2 + (i>>1)];
          az[tt][i] = (i&1) ? bfhi(uz) : bflo(uz);
          ar[tt][i] = (i&1) ? bfhi(ur) : bflo(ur);
        }
      }
    }
    // reload xa* for t+1 in place (full step of latency slack)
    xa0 = pA[0]; xa1 = pA[1]; xa2 = pA[128]; xa3 = pA[129];
    pA += 4096;

    #pragma unroll
    for (int kc=0; kc<8; kc++){
      bf16x8 a = *(const bf16x8*)&fb[kc*512 + lswz*8];   // swizzled h read
      #pragma unroll
      for (int tt=0; tt<4; tt++){
        ar[tt] = __builtin_amdgcn_mfma_f32_16x16x32_bf16(a, Ur[tt][kc], ar[tt], 0,0,0);
        az[tt] = __builtin_amdgcn_mfma_f32_16x16x32_bf16(a, Uz[tt][kc], az[tt], 0,0,0);
      }
    }
    // r, v = r*h -> LDS (swizzled write, conflict-free); z deferred to phase B
    #pragma unroll
    for (int tt=0; tt<4; tt++){
      #pragma unroll
      for (int i=0;i<4;i++){
        float rr = __builtin_amdgcn_fmed3f(fmaf(0.2f, ar[tt][i], 0.5f), 0.f, 1.f);
        float v  = rr * hprev[tt][i];
        fb[4096 + wrb + tt*256 + ((i^ix)<<3)] = (short)cvtpk(v, v);
      }
    }
    __syncthreads();

    // ---- phase B: hh = tanh(xh + (r*h)@Uh); z-epilogue hides under MFMA ----
    f32x4 ah[4];
    {
      unsigned hw_[8] = {xb0.x,xb0.y,xb0.z,xb0.w, xb1.x,xb1.y,xb1.z,xb1.w};
      #pragma unroll
      for (int tt=0; tt<4; tt++)
        #pragma unroll
        for (int i=0;i<4;i++){
          unsigned uh = hw_[tt*2 + (i>>1)];
          ah[tt][i] = (i&1) ? bfhi(uh) : bflo(uh);
        }
    }
    xb0 = pB[0]; xb1 = pB[64];       // reload in place for t+1
    pB += 2048;

    #pragma unroll
    for (int kc=0; kc<8; kc++){
      bf16x8 vv = *(const bf16x8*)&fb[4096 + kc*512 + lswz*8];
      #pragma unroll
      for (int tt=0; tt<4; tt++)
        ah[tt] = __builtin_amdgcn_mfma_f32_16x16x32_bf16(vv, Uh[tt][kc], ah[tt], 0,0,0);
    }
    // z-epilogue (independent of ah -> scheduler overlaps it with MFMA issue)
    float z8[4][4];
    #pragma unroll
    for (int tt=0; tt<4; tt++)
      #pragma unroll
      for (int i=0;i<4;i++)
        z8[tt][i] = __builtin_amdgcn_fmed3f(fmaf(0.2f, az[tt][i], 0.5f), 0.f, 1.f);
    #pragma unroll
    for (int ct=0; ct<4; ct++){
      #pragma unroll
      for (int i=0;i<4;i++){
        // tanh(p) = 1 - 2/(exp2(2*log2e*p)+1); inf/0 saturate to +/-1, no clamp
        float e  = exp2_fast(2.8853900817779268f * ah[ct][i]);
        float rc = __builtin_amdgcn_rcpf(e + 1.f);
        float hh = fmaf(-2.f, rc, 1.f);
        float hn = fmaf(z8[ct][i], hprev[ct][i] - hh, hh);
        hprev[ct][i] = hn;
        fb[wrb + ct*256 + ((i^ix)<<3)] = (short)cvtpk(hn, hn);
      }
    }
    __syncthreads();
  }

  // h_last from registers
  #pragma unroll
  for (int ct=0; ct<4; ct++)
    #pragma unroll
    for (int i=0;i<4;i++)
      out[(size_t)(b0 + q*4 + i)*256 + w2*64 + ct*16 + r16] = hprev[ct][i];
}

extern "C" void kernel_launch(void* const* d_in, const int* in_sizes, int n_in,
                              void* d_out, int out_size, void* d_ws, size_t ws_size,
                              hipStream_t stream) {
  (void)in_sizes; (void)n_in; (void)out_size; (void)ws_size;
  const float* x    = (const float*)d_in[0];
  const float* Wk   = (const float*)d_in[1];
  const float* Rk   = (const float*)d_in[2];
  const float* bias = (const float*)d_in[3];
  float* out = (float*)d_out;

  unsigned short* XA = (unsigned short*)d_ws;                 // 2048*32768 shorts
  unsigned short* XB = XA + (size_t)2048*32768;               // 2048*16384 shorts
  unsigned short* Wt = XB + (size_t)2048*16384;               // 768*256
  unsigned short* Ut = Wt + (size_t)768*256;                  // 768*256

  hipLaunchKernelGGL(transpose_k, dim3(1536),    dim3(256), 0, stream, Wk, Rk, Wt, Ut);
  hipLaunchKernelGGL(proj_k,      dim3(2048,12), dim3(256), 0, stream, x, Wt, bias, XA, XB);
  hipLaunchKernelGGL(gru_k,       dim3(4),       dim3(256), 0, stream, XA, XB, Ut, out);
}

// Round 7
// 3256.269 us; speedup vs baseline: 1.6317x; 1.6317x over previous
//
#include <hip/hip_runtime.h>

// GRU: B=64, T=2048, D=256, U=256.
//  k0: transpose weights -> bf16 [col][k]
//  k1: proj GEMM -> recurrence-native x layout. R10: grid swapped to
//      (bn=12, t=2048) so the 12 blocks sharing x[:,t,:] are dispatched
//      adjacently -> x slice L2-hit 11/12 times instead of re-fetched from
//      HBM (old order: same-t blocks 2048 apart -> ~1.6GB redundant fetch,
//      ~250us). Kernel body identical except tm/bn come from swapped dims.
//  k2: recurrence = R3 exactly (best verified: 2892us, MfmaUtil 0.70,
//      bank conflicts 0). R4 (U in LDS) and R5 (4 waves) both regressed:
//      LDS pipe is the co-bottleneck (don't add U reads) and per-wave U
//      must stay <= 192 regs (allocator breaks above).
//  (R6 run was an infra failure -- "container failed twice" -- resubmitting
//   the same source unchanged.)

#define TB 2048
#define NU 256
#define G3 768

typedef __attribute__((ext_vector_type(8))) short bf16x8;
typedef __attribute__((ext_vector_type(4))) float f32x4;

__device__ inline unsigned short f2bf(float f){
  union{float f; unsigned u;} v; v.f = f;
  unsigned r = v.u + 0x7fffu + ((v.u >> 16) & 1u);   // RNE
  return (unsigned short)(r >> 16);
}
__device__ inline unsigned pk2(float a, float b){
  return (unsigned)f2bf(a) | ((unsigned)f2bf(b) << 16);
}
__device__ inline float bflo(unsigned u){
  union{unsigned u; float f;} v; v.u = u << 16; return v.f;
}
__device__ inline float bfhi(unsigned u){
  union{unsigned u; float f;} v; v.u = u & 0xffff0000u; return v.f;
}
// single-instruction RNE f32->bf16 pack
__device__ inline unsigned cvtpk(float a, float b){
  unsigned r;
  asm("v_cvt_pk_bf16_f32 %0, %1, %2" : "=v"(r) : "v"(a), "v"(b));
  return r;
}
__device__ inline float exp2_fast(float x){
#if __has_builtin(__builtin_amdgcn_exp2f)
  return __builtin_amdgcn_exp2f(x);
#else
  float r; asm("v_exp_f32 %0, %1" : "=v"(r) : "v"(x)); return r;
#endif
}

// ---------------- k0: weight transpose to bf16 [col][k] ----------------
__global__ __launch_bounds__(256) void transpose_k(const float* __restrict__ W,
                                                   const float* __restrict__ R,
                                                   unsigned short* __restrict__ Wt,
                                                   unsigned short* __restrict__ Ut){
  int n = blockIdx.x;        // 0..1535
  int k = threadIdx.x;       // 0..255
  if (n < G3) Wt[n*NU + k] = f2bf(W[k*G3 + n]);
  else        Ut[(n-G3)*NU + k] = f2bf(R[k*G3 + (n-G3)]);
}

// ---------------- k1: projection GEMM ----------------
__global__ __launch_bounds__(256) void proj_k(const float* __restrict__ x,
                                              const unsigned short* __restrict__ Wt,
                                              const float* __restrict__ bias,
                                              unsigned short* __restrict__ XA,
                                              unsigned short* __restrict__ XB){
  __shared__ short As[4096];
  __shared__ short Bs[4096];
  __shared__ short St[4096];        // compact [chunk 0..7][lane 0..63][8]
  const int tid  = threadIdx.x;
  const int lane = tid & 63;
  const int wv   = tid >> 6;
  const int wr   = wv >> 1, wc = wv & 1;
  const int q    = lane >> 4, r16 = lane & 15;
  const int tm   = blockIdx.y;      // time step   (R10: swapped)
  const int bn   = blockIdx.x;      // 0..11 gate-col chunk (fast dim)

  f32x4 acc[2][2];
  #pragma unroll
  for (int a=0;a<2;a++)
    #pragma unroll
    for (int b=0;b<2;b++) acc[a][b] = {0.f,0.f,0.f,0.f};

  const int mA = tid >> 2, kq = tid & 3;
  const int kc32 = kq >> 1, q0 = (kq & 1) * 2;

  for (int kc0 = 0; kc0 < 256; kc0 += 64){
    {
      const float* src = x + (size_t)mA*(2048*256) + (size_t)tm*256 + kc0 + kq*16;
      float4 f0 = *(const float4*)(src);
      float4 f1 = *(const float4*)(src+4);
      float4 f2 = *(const float4*)(src+8);
      float4 f3 = *(const float4*)(src+12);
      *(uint2*)&As[kc32*2048 + q0*512     + mA*8 + 0] = make_uint2(pk2(f0.x,f0.y), pk2(f0.z,f0.w));
      *(uint2*)&As[kc32*2048 + q0*512     + mA*8 + 4] = make_uint2(pk2(f1.x,f1.y), pk2(f1.z,f1.w));
      *(uint2*)&As[kc32*2048 + (q0+1)*512 + mA*8 + 0] = make_uint2(pk2(f2.x,f2.y), pk2(f2.z,f2.w));
      *(uint2*)&As[kc32*2048 + (q0+1)*512 + mA*8 + 4] = make_uint2(pk2(f3.x,f3.y), pk2(f3.z,f3.w));
    }
    {
      const unsigned short* srcB = Wt + (size_t)(bn*64 + mA)*256 + kc0 + kq*16;
      uint4 b0v = *(const uint4*)(srcB);
      uint4 b1v = *(const uint4*)(srcB+8);
      *(uint4*)&Bs[kc32*2048 + q0*512     + mA*8] = b0v;
      *(uint4*)&Bs[kc32*2048 + (q0+1)*512 + mA*8] = b1v;
    }
    __syncthreads();
    #pragma unroll
    for (int kk = 0; kk < 2; kk++){
      bf16x8 av[2], bv[2];
      #pragma unroll
      for (int rt=0; rt<2; rt++)
        av[rt] = *(const bf16x8*)&As[kk*2048 + q*512 + (wr*32+rt*16+r16)*8];
      #pragma unroll
      for (int ct=0; ct<2; ct++)
        bv[ct] = *(const bf16x8*)&Bs[kk*2048 + q*512 + (wc*32+ct*16+r16)*8];
      #pragma unroll
      for (int rt=0; rt<2; rt++)
        #pragma unroll
        for (int ct=0; ct<2; ct++)
          acc[rt][ct] = __builtin_amdgcn_mfma_f32_16x16x32_bf16(av[rt], bv[ct], acc[rt][ct], 0,0,0);
    }
    __syncthreads();
  }

  // epilogue: +bias, stage compact recurrence-native order in St
  const int csub = (bn < 4) ? 0 : (bn < 8 ? 256 : 512);
  #pragma unroll
  for (int rt=0; rt<2; rt++){
    #pragma unroll
    for (int ct=0; ct<2; ct++){
      int colg = bn*64 + wc*32 + ct*16 + r16;
      float bb = bias[colg];
      int c = colg - csub;                 // 0..255 within z / r / h
      int wi = (c >> 5) & 1, tt2 = (c >> 4) & 1, r16g = c & 15;
      #pragma unroll
      for (int i=0;i<4;i++){
        int b = wr*32 + rt*16 + q*4 + i;   // batch
        int gg = b >> 4, lb = b & 15;
        int lane_ = (lb >> 2)*16 + r16g, ii = lb & 3;
        St[(gg*2+wi)*512 + lane_*8 + tt2*4 + ii] = (short)f2bf(acc[rt][ct][i] + bb);
      }
    }
  }
  __syncthreads();

  // disjoint coalesced stores: z -> XA slot 0, r -> XA slot 1, h -> XB
  #pragma unroll
  for (int it=0; it<2; it++){
    int idx = tid + it*256;            // 0..511
    int chunk = idx >> 6, within = idx & 63;
    int gg = chunk >> 1, wi = chunk & 1;
    int w_ = (bn & 3)*2 + wi;
    uint4 val = *(const uint4*)&St[chunk*512 + within*8];
    if (bn < 8){
      int sel = (bn < 4) ? 0 : 1;
      *((uint4*)XA + ((((size_t)tm*4+gg)*8 + w_)*64 + within)*2 + sel) = val;
    } else {
      *((uint4*)XB + (((size_t)tm*4+gg)*8 + w_)*64 + within) = val;
    }
  }
}

// ---------------- k2: recurrence (R3 exact) ----------------
__global__ __launch_bounds__(512, 2) void gru_k(const unsigned short* __restrict__ XA,
                                                const unsigned short* __restrict__ XB,
                                                const unsigned short* __restrict__ Ut,
                                                float* __restrict__ out){
  // [0..4095]=h frag-order (swizzled), [4096..8191]=r*h (swizzled)
  __shared__ short fb[8192];

  const int tid  = threadIdx.x;
  const int w    = tid >> 6;        // wave 0..7 owns unit cols [w*32, w*32+32)
  const int lane = tid & 63;
  const int q    = lane >> 4, r16 = lane & 15;
  const int g    = blockIdx.x;
  const int b0   = g * 16;

  // XOR bank swizzle (lane-constant on both sides, zero runtime cost)
  const int lswz = (lane & ~3) | ((lane & 3) ^ ((((lane >> 4) & 1) << 1) | ((lane >> 3) & 1)));
  const int ix   = ((r16 >> 3) << 1) | ((lane >> 5) & 1);
  const int wrb  = w*512 + (r16 >> 3)*128 + q*32 + (r16 & 7);   // + tt*256 + (i^ix)*8

  for (int i = tid; i < 8192; i += 512) fb[i] = 0;

  // one-time U fragment load
  bf16x8 Uz[2][8], Ur[2][8], Uh[2][8];
  #pragma unroll
  for (int tt=0; tt<2; tt++){
    int cz = w*32 + tt*16 + r16;
    #pragma unroll
    for (int kc=0; kc<8; kc++){
      Uz[tt][kc] = *(const bf16x8*)&Ut[(cz      )*256 + kc*32 + q*8];
      Ur[tt][kc] = *(const bf16x8*)&Ut[(cz + 256)*256 + kc*32 + q*8];
      Uh[tt][kc] = *(const bf16x8*)&Ut[(cz + 512)*256 + kc*32 + q*8];
    }
  }

  float hprev[2][4] = {{0.f,0.f,0.f,0.f},{0.f,0.f,0.f,0.f}};

  const uint4* pA = (const uint4*)XA + ((size_t)(g*8+w)*64 + lane)*2;
  const uint4* pB = (const uint4*)XB + ((size_t)(g*8+w)*64 + lane);

  // prologue load for t=0; loop prefetches t+1 (t=2047 over-read lands in
  // XB / Wt workspace regions -- harmless, never consumed)
  uint4 xa0 = pA[0], xa1 = pA[1];
  uint4 xb0 = pB[0];
  pA += 4096; pB += 2048;

  __syncthreads();

  #pragma unroll 1
  for (int t = 0; t < TB; t++){
    uint4 na0 = pA[0], na1 = pA[1];      // prefetch t+1: full step of slack
    uint4 nb0 = pB[0];
    pA += 4096; pB += 2048;

    unsigned xw[8] = {xa0.x,xa0.y,xa0.z,xa0.w,xa1.x,xa1.y,xa1.z,xa1.w};

    // ---- phase A: z,r MFMAs for own 32 gate cols; acc init = x ----
    f32x4 az[2], ar[2];
    #pragma unroll
    for (int tt=0; tt<2; tt++){
      #pragma unroll
      for (int i=0;i<4;i++){
        int s  = tt*4 + i;
        int sr = 8 + s;
        az[tt][i] = (s&1)  ? bfhi(xw[s>>1])  : bflo(xw[s>>1]);
        ar[tt][i] = (sr&1) ? bfhi(xw[sr>>1]) : bflo(xw[sr>>1]);
      }
    }
    #pragma unroll
    for (int kc=0; kc<8; kc++){
      bf16x8 a = *(const bf16x8*)&fb[kc*512 + lswz*8];   // swizzled read
      ar[0] = __builtin_amdgcn_mfma_f32_16x16x32_bf16(a, Ur[0][kc], ar[0], 0,0,0);
      ar[1] = __builtin_amdgcn_mfma_f32_16x16x32_bf16(a, Ur[1][kc], ar[1], 0,0,0);
      az[0] = __builtin_amdgcn_mfma_f32_16x16x32_bf16(a, Uz[0][kc], az[0], 0,0,0);
      az[1] = __builtin_amdgcn_mfma_f32_16x16x32_bf16(a, Uz[1][kc], az[1], 0,0,0);
    }
    // r, v = r*h -> LDS (swizzled write, conflict-free); z deferred to phase B
    #pragma unroll
    for (int tt=0; tt<2; tt++){
      #pragma unroll
      for (int i=0;i<4;i++){
        float rr = __builtin_amdgcn_fmed3f(fmaf(0.2f, ar[tt][i], 0.5f), 0.f, 1.f);
        float v  = rr * hprev[tt][i];
        fb[4096 + wrb + tt*256 + ((i^ix)<<3)] = (short)cvtpk(v, v);
      }
    }
    __syncthreads();

    // ---- phase B: hh = tanh(xh + (r*h)@Uh); z-epilogue hides under MFMA ----
    f32x4 ah[2];
    {
      unsigned xwb[4] = {xb0.x,xb0.y,xb0.z,xb0.w};
      #pragma unroll
      for (int ct=0; ct<2; ct++){
        #pragma unroll
        for (int i=0;i<4;i++){
          int s = ct*4 + i;
          ah[ct][i] = (s&1) ? bfhi(xwb[s>>1]) : bflo(xwb[s>>1]);
        }
      }
    }
    #pragma unroll
    for (int kc=0; kc<8; kc++){
      bf16x8 vv = *(const bf16x8*)&fb[4096 + kc*512 + lswz*8];
      ah[0] = __builtin_amdgcn_mfma_f32_16x16x32_bf16(vv, Uh[0][kc], ah[0], 0,0,0);
      ah[1] = __builtin_amdgcn_mfma_f32_16x16x32_bf16(vv, Uh[1][kc], ah[1], 0,0,0);
    }
    // z-epilogue (independent of ah -> scheduler overlaps it with MFMA issue)
    float z8[2][4];
    #pragma unroll
    for (int tt=0; tt<2; tt++)
      #pragma unroll
      for (int i=0;i<4;i++)
        z8[tt][i] = __builtin_amdgcn_fmed3f(fmaf(0.2f, az[tt][i], 0.5f), 0.f, 1.f);
    #pragma unroll
    for (int ct=0; ct<2; ct++){
      #pragma unroll
      for (int i=0;i<4;i++){
        // tanh(p) = 1 - 2/(exp2(2*log2e*p)+1); inf/0 saturate to +/-1, no clamp
        float e  = exp2_fast(2.8853900817779268f * ah[ct][i]);
        float rc = __builtin_amdgcn_rcpf(e + 1.f);
        float hh = fmaf(-2.f, rc, 1.f);
        float hn = fmaf(z8[ct][i], hprev[ct][i] - hh, hh);
        hprev[ct][i] = hn;
        fb[wrb + ct*256 + ((i^ix)<<3)] = (short)cvtpk(hn, hn);
      }
    }
    __syncthreads();

    xa0 = na0; xa1 = na1; xb0 = nb0;
  }

  // h_last from registers
  #pragma unroll
  for (int ct=0; ct<2; ct++)
    #pragma unroll
    for (int i=0;i<4;i++)
      out[(size_t)(b0 + q*4 + i)*256 + w*32 + ct*16 + r16] = hprev[ct][i];
}

extern "C" void kernel_launch(void* const* d_in, const int* in_sizes, int n_in,
                              void* d_out, int out_size, void* d_ws, size_t ws_size,
                              hipStream_t stream) {
  (void)in_sizes; (void)n_in; (void)out_size; (void)ws_size;
  const float* x    = (const float*)d_in[0];
  const float* Wk   = (const float*)d_in[1];
  const float* Rk   = (const float*)d_in[2];
  const float* bias = (const float*)d_in[3];
  float* out = (float*)d_out;

  unsigned short* XA = (unsigned short*)d_ws;                 // 2048*32768 shorts
  unsigned short* XB = XA + (size_t)2048*32768;               // 2048*16384 shorts
  unsigned short* Wt = XB + (size_t)2048*16384;               // 768*256
  unsigned short* Ut = Wt + (size_t)768*256;                  // 768*256

  hipLaunchKernelGGL(transpose_k, dim3(1536),    dim3(256), 0, stream, Wk, Rk, Wt, Ut);
  hipLaunchKernelGGL(proj_k,      dim3(12,2048), dim3(256), 0, stream, x, Wt, bias, XA, XB);
  hipLaunchKernelGGL(gru_k,       dim3(4),       dim3(512), 0, stream, XA, XB, Ut, out);
}